// Round 4
// baseline (354.062 us; speedup 1.0000x reference)
//
#include <hip/hip_runtime.h>

#define DHW (64*128*128)
#define MIR 32

// accumulator layout in d_ws (floats)
#define OFF_CEM   0        // [MIR][49]: nll, cardp[2][8], inter[2][8], cardg[2][8]
#define OFF_SEGM  1568     // [MIR][2][306]: cnum[17][16] (slots 16..271), wsum[17] (272..288), cnt[17] (289..305)
#define OFF_PULLM 21152    // [MIR][2][17]
#define OFF_CTR   22240    // [2][17][16]
#define OFF_CNT   22784    // [2][17]
#define ACC_FLOATS 22818

typedef __bf16 bf16x8 __attribute__((ext_vector_type(8)));
typedef float f32x4 __attribute__((ext_vector_type(4)));
union FragU { short s[8]; bf16x8 v; };

__device__ inline short f2bf(float f) {   // RTNE float->bf16
    union { float f; unsigned u; } v; v.f = f;
    unsigned r = v.u + 0x7FFF + ((v.u >> 16) & 1);
    return (short)(r >> 16);
}

// boundary bits for 4 consecutive-in-x voxels (x % 4 == 0), early-exit
__device__ inline unsigned edge4(const int* __restrict__ L, int vb, int4 c) {
    int x = vb & 127, y = (vb >> 7) & 127, z = vb >> 14;
    int z0 = max(z - 1, 0), z1 = min(z + 1, 63);
    int y0 = max(y - 1, 0), y1 = min(y + 1, 127);
    int xm = max(x - 1, 0), xp = min(x + 4, 127);
    unsigned b0 = 0, b1 = 0, b2 = 0, b3 = 0;
    for (int zz = z0; zz <= z1; ++zz) {
        for (int yy = y0; yy <= y1; ++yy) {
            const int* row = L + (zz << 14) + (yy << 7);
            int4 r = *reinterpret_cast<const int4*>(&row[x]);
            int rm = row[xm], rp = row[xp];
            b0 |= (rm != c.x) | (r.x != c.x) | (r.y != c.x);
            b1 |= (r.x != c.y) | (r.y != c.y) | (r.z != c.y);
            b2 |= (r.y != c.z) | (r.z != c.z) | (r.w != c.z);
            b3 |= (r.z != c.w) | (r.w != c.w) | (rp != c.w);
            if (b0 & b1 & b2 & b3) return 0xF;
        }
    }
    return b0 | (b1 << 1) | (b2 << 2) | (b3 << 3);
}

__global__ void zero_kernel(float* acc) {
    int i = blockIdx.x * 1024 + threadIdx.x;
    if (i < ACC_FLOATS) acc[i] = 0.0f;
}

// ---------------- front: ce_dice (role 0) + segsum (role 1), concurrent ----------------
__global__ __launch_bounds__(256) void front_kernel(const float* __restrict__ logits,
                                                    const float* __restrict__ embed,
                                                    const int* __restrict__ cls,
                                                    const int* __restrict__ labels,
                                                    float* __restrict__ acc) {
    __shared__ float sh[25];
    __shared__ float cacc[288];
    int role = blockIdx.x & 1;
    int pos = blockIdx.x >> 1;       // [0, 2048)
    int b = pos & 1;
    int blk = pos >> 1;              // [0, 1024)
    int mir = blk & (MIR - 1);
    int tid = threadIdx.x;

    if (role == 0) {
        // ---------- CE + Dice ----------
        int vb = (blk * 256 + tid) * 4;
        const float* lg = logits + (size_t)b * 8 * DHW;
        const int* cl = cls + (size_t)b * DHW;

        float4 xc[8];
#pragma unroll
        for (int c = 0; c < 8; ++c)
            xc[c] = *reinterpret_cast<const float4*>(&lg[(size_t)c * DHW + vb]);
        int4 t4 = *reinterpret_cast<const int4*>(&cl[vb]);
        int tt[4] = {t4.x, t4.y, t4.z, t4.w};

        float nll = 0.f, cardp[8], inter[8], cardg[8];
#pragma unroll
        for (int c = 0; c < 8; ++c) { cardp[c] = 0.f; inter[c] = 0.f; cardg[c] = 0.f; }

#pragma unroll
        for (int j = 0; j < 4; ++j) {
            float x[8];
#pragma unroll
            for (int c = 0; c < 8; ++c) x[c] = ((const float*)&xc[c])[j];
            int t = tt[j];
            bool valid = (t != -100);
            float mx = x[0];
#pragma unroll
            for (int c = 1; c < 8; ++c) mx = fmaxf(mx, x[c]);
            float e[8], s = 0.f;
#pragma unroll
            for (int c = 0; c < 8; ++c) { e[c] = __expf(x[c] - mx); s += e[c]; }
            float inv = 1.0f / s;
            float lse = __logf(s);
            if (valid) {
#pragma unroll
                for (int c = 0; c < 8; ++c) {
                    float p = e[c] * inv;
                    cardp[c] += p;
                    if (t == c) { inter[c] += p; cardg[c] += 1.f; nll += mx + lse - x[c]; }
                }
            }
        }

        if (tid < 25) sh[tid] = 0.f;
        __syncthreads();
        int lane = tid & 63;
        float vals[25];
        vals[0] = nll;
#pragma unroll
        for (int c = 0; c < 8; ++c) { vals[1 + c] = cardp[c]; vals[9 + c] = inter[c]; vals[17 + c] = cardg[c]; }
#pragma unroll
        for (int i = 0; i < 25; ++i) {
            float r = vals[i];
#pragma unroll
            for (int off = 32; off > 0; off >>= 1) r += __shfl_down(r, off, 64);
            if (lane == 0) atomicAdd(&sh[i], r);
        }
        __syncthreads();
        if (tid < 25) {
            int dst;
            if (tid == 0) dst = 0;
            else if (tid < 9) dst = 1 + b * 8 + (tid - 1);
            else if (tid < 17) dst = 17 + b * 8 + (tid - 9);
            else dst = 33 + b * 8 + (tid - 17);
            atomicAdd(&acc[OFF_CEM + mir * 49 + dst], sh[tid]);
        }
    } else {
        // ---------- segment sums via MFMA, inline edge weights ----------
        int lane = tid & 63;
        int wv = tid >> 6;
        int m = lane & 15;       // A-row (label m+1) / B-col (channel m)
        int quad = lane >> 4;

        const int* L = labels + (size_t)b * DHW;
        const float* E = embed + (size_t)b * 16 * DHW + (size_t)m * DHW;

        int waveId = blk * 4 + wv;
        int off = waveId * 256 + quad * 8;   // 8 iters x 32 voxels per wave

        f32x4 acc_c = {0.f, 0.f, 0.f, 0.f};
        f32x4 acc_w = {0.f, 0.f, 0.f, 0.f};
        f32x4 acc_n = {0.f, 0.f, 0.f, 0.f};

        FragU ones_col;
#pragma unroll
        for (int j = 0; j < 8; ++j) ones_col.s[j] = (m == 0) ? (short)0x3F80 : (short)0;

        int4 l0 = *reinterpret_cast<const int4*>(&L[off]);
        int4 l1 = *reinterpret_cast<const int4*>(&L[off + 4]);
        float4 f0 = *reinterpret_cast<const float4*>(&E[off]);
        float4 f1 = *reinterpret_cast<const float4*>(&E[off + 4]);

        for (int i = 0; i < 8; ++i) {
            int4 nl0, nl1; float4 nf0, nf1;
            if (i < 7) {
                int noff = off + 32;
                nl0 = *reinterpret_cast<const int4*>(&L[noff]);
                nl1 = *reinterpret_cast<const int4*>(&L[noff + 4]);
                nf0 = *reinterpret_cast<const float4*>(&E[noff]);
                nf1 = *reinterpret_cast<const float4*>(&E[noff + 4]);
            }
            unsigned eb = edge4(L, off, l0) | (edge4(L, off + 4, l1) << 4);

            int ls[8] = {l0.x, l0.y, l0.z, l0.w, l1.x, l1.y, l1.z, l1.w};
            float fs[8] = {f0.x, f0.y, f0.z, f0.w, f1.x, f1.y, f1.z, f1.w};

            FragU a, a2, bf;
#pragma unroll
            for (int j = 0; j < 8; ++j) {
                short w = ((eb >> j) & 1) ? (short)0x4120 : (short)0x3F80;   // 10.0 : 1.0
                bool hit = (ls[j] == m + 1);
                a.s[j]  = hit ? w : (short)0;
                a2.s[j] = hit ? (short)0x3F80 : (short)0;
                bf.s[j] = f2bf(fs[j]);
            }
            acc_c = __builtin_amdgcn_mfma_f32_16x16x32_bf16(a.v, bf.v, acc_c, 0, 0, 0);
            acc_w = __builtin_amdgcn_mfma_f32_16x16x32_bf16(a.v, ones_col.v, acc_w, 0, 0, 0);
            acc_n = __builtin_amdgcn_mfma_f32_16x16x32_bf16(a2.v, ones_col.v, acc_n, 0, 0, 0);

            l0 = nl0; l1 = nl1; f0 = nf0; f1 = nf1;
            off += 32;
        }

        for (int i = tid; i < 288; i += 256) cacc[i] = 0.f;
        __syncthreads();
#pragma unroll
        for (int r = 0; r < 4; ++r)
            atomicAdd(&cacc[(quad * 4 + r) * 16 + m], acc_c[r]);
        if (m == 0) {
#pragma unroll
            for (int r = 0; r < 4; ++r) {
                atomicAdd(&cacc[256 + quad * 4 + r], acc_w[r]);
                atomicAdd(&cacc[272 + quad * 4 + r], acc_n[r]);
            }
        }
        __syncthreads();
        {
            float* segbase = acc + OFF_SEGM + mir * 612 + b * 306;
            atomicAdd(&segbase[16 + tid], cacc[tid]);
            if (tid < 16) atomicAdd(&segbase[272 + 1 + tid], cacc[256 + tid]);
            else if (tid < 32) atomicAdd(&segbase[289 + 1 + (tid - 16)], cacc[256 + tid]);
        }
    }
}

// ---------------- centers: sum mirrors, divide ----------------
__global__ __launch_bounds__(1024) void centers_kernel(float* acc) {
    int tid = threadIdx.x;
    if (tid < 544) {
        int b = tid / 272, r = tid % 272;       // r = k*16+c
        int k = r >> 4;
        float cn = 0.f, ws = 0.f;
        for (int mv = 0; mv < MIR; ++mv) {
            const float* segbase = acc + OFF_SEGM + mv * 612 + b * 306;
            if (r >= 16) cn += segbase[r];
            ws += segbase[272 + k];
        }
        acc[OFF_CTR + tid] = (r >= 16) ? cn / (ws + 1e-8f) : 0.f;
    } else if (tid < 578) {
        int j = tid - 544;                       // b*17+k
        int b = j / 17, k = j % 17;
        float s = 0.f;
        for (int mv = 0; mv < MIR; ++mv)
            s += acc[OFF_SEGM + mv * 612 + b * 306 + 289 + k];
        acc[OFF_CNT + j] = s;
    }
}

// ---------------- pass 2: pull, inline edge weights ----------------
__global__ __launch_bounds__(256) void pull_kernel(const float* __restrict__ embed,
                                                   const int* __restrict__ labels,
                                                   float* __restrict__ acc) {
    int b = blockIdx.x & 1;
    int blk = blockIdx.x >> 1;      // [0, 1024)
    int tid = threadIdx.x;
    int wv = tid >> 6;
    __shared__ float ctr[17 * 16];
    __shared__ float ps[4 * 20];
    for (int i = tid; i < 272; i += 256) ctr[i] = acc[OFF_CTR + b * 272 + i];
    for (int i = tid; i < 80; i += 256) ps[i] = 0.f;
    __syncthreads();

    const int* L = labels + (size_t)b * DHW;
    const float* E = embed + (size_t)b * 16 * DHW;
    int vb = (blk * 256 + tid) * 4;

    int4 l4 = *reinterpret_cast<const int4*>(&L[vb]);
    int l[4] = {l4.x, l4.y, l4.z, l4.w};

    float4 e4[16];
#pragma unroll
    for (int c = 0; c < 16; ++c)
        e4[c] = *reinterpret_cast<const float4*>(&E[(size_t)c * DHW + vb]);

    unsigned eb = edge4(L, vb, l4);

#pragma unroll
    for (int j = 0; j < 4; ++j) {
        if (l[j] != 0) {
            float w = ((eb >> j) & 1) ? 10.f : 1.f;
            const float4* cg = reinterpret_cast<const float4*>(&ctr[l[j] * 16]);
            float d2 = 0.f;
#pragma unroll
            for (int q = 0; q < 4; ++q) {
                float4 cv = cg[q];
                float d0 = ((const float*)&e4[4 * q + 0])[j] - cv.x;
                float d1 = ((const float*)&e4[4 * q + 1])[j] - cv.y;
                float dd2 = ((const float*)&e4[4 * q + 2])[j] - cv.z;
                float d3 = ((const float*)&e4[4 * q + 3])[j] - cv.w;
                d2 += d0 * d0 + d1 * d1 + dd2 * dd2 + d3 * d3;
            }
            float d = fmaxf(sqrtf(d2) - 0.5f, 0.f);
            atomicAdd(&ps[wv * 20 + l[j]], d * d * w);
        }
    }
    __syncthreads();
    if (tid >= 1 && tid < 17) {
        float v = ps[tid] + ps[20 + tid] + ps[40 + tid] + ps[60 + tid];
        int mir = blk & (MIR - 1);
        if (v != 0.f) atomicAdd(&acc[OFF_PULLM + mir * 34 + b * 17 + tid], v);
    }
}

// ---------------- finalize ----------------
__global__ __launch_bounds__(256) void finalize_kernel(const float* __restrict__ acc, float* __restrict__ out) {
    __shared__ float s_ce[49], s_pl[34];
    __shared__ float sh_push[2], sh_norm[2], sh_pull[2], sh_npres[2];
    int tid = threadIdx.x;
    if (tid < 49) {
        float s = 0.f;
        for (int mv = 0; mv < MIR; ++mv) s += acc[OFF_CEM + mv * 49 + tid];
        s_ce[tid] = s;
    }
    if (tid >= 64 && tid < 98) {
        int j = tid - 64;
        float s = 0.f;
        for (int mv = 0; mv < MIR; ++mv) s += acc[OFF_PULLM + mv * 34 + j];
        s_pl[j] = s;
    }
    if (tid < 2) { sh_push[tid] = 0.f; sh_norm[tid] = 0.f; sh_pull[tid] = 0.f; sh_npres[tid] = 0.f; }
    __syncthreads();

    if (tid < 32) {
        int b = tid >> 4, k = (tid & 15) + 1;
        float cnt = acc[OFF_CNT + b * 17 + k];
        if (cnt > 0.f) {
            atomicAdd(&sh_npres[b], 1.f);
            atomicAdd(&sh_pull[b], s_pl[b * 17 + k] / fmaxf(cnt, 1.f));
            const float* c = &acc[OFF_CTR + (b * 17 + k) * 16];
            float n2 = 0.f;
            for (int i = 0; i < 16; ++i) n2 += c[i] * c[i];
            atomicAdd(&sh_norm[b], sqrtf(n2));
        }
    }
    for (int t = tid; t < 240; t += blockDim.x) {
        int b = t / 120, p = t % 120;
        int i = 1, rem = p;
        while (rem >= (16 - i)) { rem -= (16 - i); ++i; }
        int j = i + 1 + rem;
        bool pi = acc[OFF_CNT + b * 17 + i] > 0.f;
        bool pj = acc[OFF_CNT + b * 17 + j] > 0.f;
        if (pi && pj) {
            const float* ci = &acc[OFF_CTR + (b * 17 + i) * 16];
            const float* cj = &acc[OFF_CTR + (b * 17 + j) * 16];
            float d2 = 0.f;
            for (int c = 0; c < 16; ++c) { float dd = ci[c] - cj[c]; d2 += dd * dd; }
            float r = fmaxf(3.0f - sqrtf(d2), 0.f);
            atomicAdd(&sh_push[b], r * r);
        }
    }
    __syncthreads();
    if (tid == 0) {
        float nll = s_ce[0];
        float vcnt = 0.f;
        for (int i = 0; i < 16; ++i) vcnt += s_ce[33 + i];
        float ce = nll / fmaxf(vcnt, 1.f);
        float dsum = 0.f;
        for (int i = 0; i < 16; ++i) {
            float it = s_ce[17 + i], cp = s_ce[1 + i], cg = s_ce[33 + i];
            dsum += (2.f * it + 1e-5f) / (cp + cg + 1e-5f);
        }
        float dice = 1.f - dsum / 16.f;
        float lp = 0.f, lpu = 0.f, ln = 0.f, val = 0.f;
        for (int b = 0; b < 2; ++b) {
            float npres = sh_npres[b];
            lp += sh_pull[b];
            float npairs = npres * (npres - 1.f) * 0.5f;
            lpu += (npairs > 0.f) ? sh_push[b] / fmaxf(npairs, 1.f) : 0.f;
            ln += (npres > 0.f) ? sh_norm[b] / fmaxf(npres, 1.f) : 0.f;
            val += (npres > 0.f) ? 1.f : 0.f;
        }
        float n = fmaxf(val, 1.f);
        float ins = (1.0f * lp + 1.0f * lpu + 0.001f * ln) / n;
        float sem = ce + dice;
        out[0] = sem + ins;
        out[1] = sem;
        out[2] = ce;
        out[3] = dice;
        out[4] = ins;
    }
}

extern "C" void kernel_launch(void* const* d_in, const int* in_sizes, int n_in,
                              void* d_out, int out_size, void* d_ws, size_t ws_size,
                              hipStream_t stream) {
    const float* sem = (const float*)d_in[0];
    const float* emb = (const float*)d_in[1];
    const int* cls = (const int*)d_in[2];
    const int* lab = (const int*)d_in[3];
    float* out = (float*)d_out;
    float* acc = (float*)d_ws;

    hipLaunchKernelGGL(zero_kernel, dim3(23), dim3(1024), 0, stream, acc);
    hipLaunchKernelGGL(front_kernel, dim3(4096), dim3(256), 0, stream, sem, emb, cls, lab, acc);
    hipLaunchKernelGGL(centers_kernel, dim3(1), dim3(1024), 0, stream, acc);
    hipLaunchKernelGGL(pull_kernel, dim3(2048), dim3(256), 0, stream, emb, lab, acc);
    hipLaunchKernelGGL(finalize_kernel, dim3(1), dim3(256), 0, stream, acc, out);
}

// Round 5
// 305.866 us; speedup vs baseline: 1.1576x; 1.1576x over previous
//
#include <hip/hip_runtime.h>

#define DHW (64*128*128)
#define MIR 32

// accumulator layout in d_ws (floats)
#define OFF_CEM   0        // [MIR][49]: nll, cardp[2][8], inter[2][8], cardg[2][8]
#define OFF_SEGM  1568     // [MIR][2][306]: cnum[17][16] (slots 16..271), wsum[17] (272..288), cnt[17] (289..305)
#define OFF_PULLM 21152    // [MIR][2][17]
#define OFF_CTR   22240    // [2][17][16]
#define OFF_CNT   22784    // [2][17]
#define ACC_FLOATS 22818

typedef __bf16 bf16x8 __attribute__((ext_vector_type(8)));
typedef float f32x4 __attribute__((ext_vector_type(4)));
union FragU { short s[8]; bf16x8 v; };

__device__ inline short f2bf(float f) {   // RTNE float->bf16
    union { float f; unsigned u; } v; v.f = f;
    unsigned r = v.u + 0x7FFF + ((v.u >> 16) & 1);
    return (short)(r >> 16);
}

// boundary bits for 4 consecutive-in-x voxels (x % 4 == 0), early-exit
__device__ inline unsigned edge4(const int* __restrict__ L, int vb, int4 c) {
    int x = vb & 127, y = (vb >> 7) & 127, z = vb >> 14;
    int z0 = max(z - 1, 0), z1 = min(z + 1, 63);
    int y0 = max(y - 1, 0), y1 = min(y + 1, 127);
    int xm = max(x - 1, 0), xp = min(x + 4, 127);
    unsigned b0 = 0, b1 = 0, b2 = 0, b3 = 0;
    for (int zz = z0; zz <= z1; ++zz) {
        for (int yy = y0; yy <= y1; ++yy) {
            const int* row = L + (zz << 14) + (yy << 7);
            int4 r = *reinterpret_cast<const int4*>(&row[x]);
            int rm = row[xm], rp = row[xp];
            b0 |= (rm != c.x) | (r.x != c.x) | (r.y != c.x);
            b1 |= (r.x != c.y) | (r.y != c.y) | (r.z != c.y);
            b2 |= (r.y != c.z) | (r.z != c.z) | (r.w != c.z);
            b3 |= (r.z != c.w) | (r.w != c.w) | (rp != c.w);
            if (b0 & b1 & b2 & b3) return 0xF;
        }
    }
    return b0 | (b1 << 1) | (b2 << 2) | (b3 << 3);
}

__global__ void zero_kernel(float* acc) {
    int i = blockIdx.x * 1024 + threadIdx.x;
    if (i < ACC_FLOATS) acc[i] = 0.0f;
}

// ---------------- ce_dice role (half-volume per phase) ----------------
__device__ void ce_role(const float* __restrict__ logits, const int* __restrict__ cls,
                        float* __restrict__ acc, int b, int blk, float* sh) {
    int tid = threadIdx.x;
    int mir = blk & (MIR - 1);
    int vb = (blk * 256 + tid) * 4;
    const float* lg = logits + (size_t)b * 8 * DHW;
    const int* cl = cls + (size_t)b * DHW;

    float4 xc[8];
#pragma unroll
    for (int c = 0; c < 8; ++c)
        xc[c] = *reinterpret_cast<const float4*>(&lg[(size_t)c * DHW + vb]);
    int4 t4 = *reinterpret_cast<const int4*>(&cl[vb]);
    int tt[4] = {t4.x, t4.y, t4.z, t4.w};

    float nll = 0.f, cardp[8], inter[8], cardg[8];
#pragma unroll
    for (int c = 0; c < 8; ++c) { cardp[c] = 0.f; inter[c] = 0.f; cardg[c] = 0.f; }

#pragma unroll
    for (int j = 0; j < 4; ++j) {
        float x[8];
#pragma unroll
        for (int c = 0; c < 8; ++c) x[c] = ((const float*)&xc[c])[j];
        int t = tt[j];
        bool valid = (t != -100);
        float mx = x[0];
#pragma unroll
        for (int c = 1; c < 8; ++c) mx = fmaxf(mx, x[c]);
        float e[8], s = 0.f;
#pragma unroll
        for (int c = 0; c < 8; ++c) { e[c] = __expf(x[c] - mx); s += e[c]; }
        float inv = 1.0f / s;
        float lse = __logf(s);
        if (valid) {
#pragma unroll
            for (int c = 0; c < 8; ++c) {
                float p = e[c] * inv;
                cardp[c] += p;
                if (t == c) { inter[c] += p; cardg[c] += 1.f; nll += mx + lse - x[c]; }
            }
        }
    }

    if (tid < 25) sh[tid] = 0.f;
    __syncthreads();
    int lane = tid & 63;
    float vals[25];
    vals[0] = nll;
#pragma unroll
    for (int c = 0; c < 8; ++c) { vals[1 + c] = cardp[c]; vals[9 + c] = inter[c]; vals[17 + c] = cardg[c]; }
#pragma unroll
    for (int i = 0; i < 25; ++i) {
        float r = vals[i];
#pragma unroll
        for (int off = 32; off > 0; off >>= 1) r += __shfl_down(r, off, 64);
        if (lane == 0) atomicAdd(&sh[i], r);
    }
    __syncthreads();
    if (tid < 25) {
        int dst;
        if (tid == 0) dst = 0;
        else if (tid < 9) dst = 1 + b * 8 + (tid - 1);
        else if (tid < 17) dst = 17 + b * 8 + (tid - 9);
        else dst = 33 + b * 8 + (tid - 17);
        atomicAdd(&acc[OFF_CEM + mir * 49 + dst], sh[tid]);
    }
}

// ---------------- phase A: segsum (2/3 of blocks) + ce half 1 ----------------
__global__ __launch_bounds__(256) void phaseA_kernel(const float* __restrict__ logits,
                                                     const float* __restrict__ embed,
                                                     const int* __restrict__ cls,
                                                     const int* __restrict__ labels,
                                                     float* __restrict__ acc) {
    __shared__ float smem[352];
    int x = blockIdx.x;
    int g = x / 3, r3 = x % 3;
    int tid = threadIdx.x;

    if (r3 == 2) {              // ce role, first half: blk in [0,512)
        int ce_idx = g;         // [0,1024)
        ce_role(logits, cls, acc, ce_idx >> 9, (ce_idx & 511), smem);
        return;
    }
    // seg role
    int seg_idx = g * 2 + r3;   // [0,2048)
    int b = seg_idx & 1;
    int blk = seg_idx >> 1;     // [0,1024)
    int mir = blk & (MIR - 1);
    int lane = tid & 63;
    int wv = tid >> 6;
    int m = lane & 15;          // A-row (label m+1) / B-col (channel m)
    int quad = lane >> 4;

    const int* L = labels + (size_t)b * DHW;
    const float* E = embed + (size_t)b * 16 * DHW + (size_t)m * DHW;

    int waveId = blk * 4 + wv;
    int wavebase = waveId * 256;

    // per-lane edge bits for this wave's 256 voxels (lane owns voxels [4*lane, 4*lane+4))
    unsigned eb_own;
    {
        int own_off = wavebase + lane * 4;
        int4 lo = *reinterpret_cast<const int4*>(&L[own_off]);
        eb_own = edge4(L, own_off, lo);
    }

    int off = wavebase + quad * 8;

    f32x4 acc_c = {0.f, 0.f, 0.f, 0.f};
    f32x4 acc_w = {0.f, 0.f, 0.f, 0.f};
    f32x4 acc_n = {0.f, 0.f, 0.f, 0.f};

    FragU ones_col;
#pragma unroll
    for (int j = 0; j < 8; ++j) ones_col.s[j] = (m == 0) ? (short)0x3F80 : (short)0;

    int4 l0 = *reinterpret_cast<const int4*>(&L[off]);
    int4 l1 = *reinterpret_cast<const int4*>(&L[off + 4]);
    float4 f0 = *reinterpret_cast<const float4*>(&E[off]);
    float4 f1 = *reinterpret_cast<const float4*>(&E[off + 4]);

    for (int i = 0; i < 8; ++i) {
        int4 nl0, nl1; float4 nf0, nf1;
        if (i < 7) {
            int noff = off + 32;
            nl0 = *reinterpret_cast<const int4*>(&L[noff]);
            nl1 = *reinterpret_cast<const int4*>(&L[noff + 4]);
            nf0 = *reinterpret_cast<const float4*>(&E[noff]);
            nf1 = *reinterpret_cast<const float4*>(&E[noff + 4]);
        }
        // fetch edge bits for the 8 voxels this lane feeds into the MFMA K-slice
        int s0 = i * 8 + quad * 2;
        unsigned ebA = (unsigned)__shfl((int)eb_own, s0, 64);
        unsigned ebB = (unsigned)__shfl((int)eb_own, s0 + 1, 64);
        unsigned eb = (ebA & 0xF) | ((ebB & 0xF) << 4);

        int ls[8] = {l0.x, l0.y, l0.z, l0.w, l1.x, l1.y, l1.z, l1.w};
        float fs[8] = {f0.x, f0.y, f0.z, f0.w, f1.x, f1.y, f1.z, f1.w};

        FragU a, a2, bf;
#pragma unroll
        for (int j = 0; j < 8; ++j) {
            short w = ((eb >> j) & 1) ? (short)0x4120 : (short)0x3F80;   // 10.0 : 1.0
            bool hit = (ls[j] == m + 1);
            a.s[j]  = hit ? w : (short)0;
            a2.s[j] = hit ? (short)0x3F80 : (short)0;
            bf.s[j] = f2bf(fs[j]);
        }
        acc_c = __builtin_amdgcn_mfma_f32_16x16x32_bf16(a.v, bf.v, acc_c, 0, 0, 0);
        acc_w = __builtin_amdgcn_mfma_f32_16x16x32_bf16(a.v, ones_col.v, acc_w, 0, 0, 0);
        acc_n = __builtin_amdgcn_mfma_f32_16x16x32_bf16(a2.v, ones_col.v, acc_n, 0, 0, 0);

        l0 = nl0; l1 = nl1; f0 = nf0; f1 = nf1;
        off += 32;
    }

    float* cacc = smem;
    for (int i = tid; i < 288; i += 256) cacc[i] = 0.f;
    __syncthreads();
#pragma unroll
    for (int r = 0; r < 4; ++r)
        atomicAdd(&cacc[(quad * 4 + r) * 16 + m], acc_c[r]);
    if (m == 0) {
#pragma unroll
        for (int r = 0; r < 4; ++r) {
            atomicAdd(&cacc[256 + quad * 4 + r], acc_w[r]);
            atomicAdd(&cacc[272 + quad * 4 + r], acc_n[r]);
        }
    }
    __syncthreads();
    {
        float* segbase = acc + OFF_SEGM + mir * 612 + b * 306;
        atomicAdd(&segbase[16 + tid], cacc[tid]);
        if (tid < 16) atomicAdd(&segbase[272 + 1 + tid], cacc[256 + tid]);
        else if (tid < 32) atomicAdd(&segbase[289 + 1 + (tid - 16)], cacc[256 + tid]);
    }
}

// ---------------- centers: sum mirrors, divide ----------------
__global__ __launch_bounds__(1024) void centers_kernel(float* acc) {
    int tid = threadIdx.x;
    if (tid < 544) {
        int b = tid / 272, r = tid % 272;       // r = k*16+c
        int k = r >> 4;
        float cn = 0.f, ws = 0.f;
        for (int mv = 0; mv < MIR; ++mv) {
            const float* segbase = acc + OFF_SEGM + mv * 612 + b * 306;
            if (r >= 16) cn += segbase[r];
            ws += segbase[272 + k];
        }
        acc[OFF_CTR + tid] = (r >= 16) ? cn / (ws + 1e-8f) : 0.f;
    } else if (tid < 578) {
        int j = tid - 544;                       // b*17+k
        int b = j / 17, k = j % 17;
        float s = 0.f;
        for (int mv = 0; mv < MIR; ++mv)
            s += acc[OFF_SEGM + mv * 612 + b * 306 + 289 + k];
        acc[OFF_CNT + j] = s;
    }
}

// ---------------- phase B: pull (2/3 of blocks) + ce half 2 ----------------
__global__ __launch_bounds__(256) void phaseB_kernel(const float* __restrict__ logits,
                                                     const float* __restrict__ embed,
                                                     const int* __restrict__ cls,
                                                     const int* __restrict__ labels,
                                                     float* __restrict__ acc) {
    __shared__ float smem[352];
    int x = blockIdx.x;
    int g = x / 3, r3 = x % 3;
    int tid = threadIdx.x;

    if (r3 == 2) {              // ce role, second half: blk in [512,1024)
        int ce_idx = g;
        ce_role(logits, cls, acc, ce_idx >> 9, (ce_idx & 511) + 512, smem);
        return;
    }
    // pull role
    int pull_idx = g * 2 + r3;  // [0,2048)
    int b = pull_idx & 1;
    int blk = pull_idx >> 1;    // [0,1024)
    int wv = tid >> 6;
    float* ctr = smem;          // 272
    float* ps = smem + 272;     // 80
    for (int i = tid; i < 272; i += 256) ctr[i] = acc[OFF_CTR + b * 272 + i];
    for (int i = tid; i < 80; i += 256) ps[i] = 0.f;
    __syncthreads();

    const int* L = labels + (size_t)b * DHW;
    const float* E = embed + (size_t)b * 16 * DHW;
    int vb = (blk * 256 + tid) * 4;

    int4 l4 = *reinterpret_cast<const int4*>(&L[vb]);
    int l[4] = {l4.x, l4.y, l4.z, l4.w};
    unsigned eb = edge4(L, vb, l4);

    float d2a[4] = {0.f, 0.f, 0.f, 0.f};
#pragma unroll
    for (int q = 0; q < 4; ++q) {
        float4 e0 = *reinterpret_cast<const float4*>(&E[(size_t)(4 * q + 0) * DHW + vb]);
        float4 e1 = *reinterpret_cast<const float4*>(&E[(size_t)(4 * q + 1) * DHW + vb]);
        float4 e2 = *reinterpret_cast<const float4*>(&E[(size_t)(4 * q + 2) * DHW + vb]);
        float4 e3 = *reinterpret_cast<const float4*>(&E[(size_t)(4 * q + 3) * DHW + vb]);
#pragma unroll
        for (int j = 0; j < 4; ++j) {
            if (l[j] != 0) {
                float4 cv = *reinterpret_cast<const float4*>(&ctr[l[j] * 16 + q * 4]);
                float d0 = ((const float*)&e0)[j] - cv.x;
                float d1 = ((const float*)&e1)[j] - cv.y;
                float d2 = ((const float*)&e2)[j] - cv.z;
                float d3 = ((const float*)&e3)[j] - cv.w;
                d2a[j] += d0 * d0 + d1 * d1 + d2 * d2 + d3 * d3;
            }
        }
    }

#pragma unroll
    for (int j = 0; j < 4; ++j) {
        if (l[j] != 0) {
            float w = ((eb >> j) & 1) ? 10.f : 1.f;
            float d = fmaxf(sqrtf(d2a[j]) - 0.5f, 0.f);
            atomicAdd(&ps[wv * 20 + l[j]], d * d * w);
        }
    }
    __syncthreads();
    if (tid >= 1 && tid < 17) {
        float v = ps[tid] + ps[20 + tid] + ps[40 + tid] + ps[60 + tid];
        int mir = blk & (MIR - 1);
        if (v != 0.f) atomicAdd(&acc[OFF_PULLM + mir * 34 + b * 17 + tid], v);
    }
}

// ---------------- finalize ----------------
__global__ __launch_bounds__(256) void finalize_kernel(const float* __restrict__ acc, float* __restrict__ out) {
    __shared__ float s_ce[49], s_pl[34];
    __shared__ float sh_push[2], sh_norm[2], sh_pull[2], sh_npres[2];
    int tid = threadIdx.x;
    if (tid < 49) {
        float s = 0.f;
        for (int mv = 0; mv < MIR; ++mv) s += acc[OFF_CEM + mv * 49 + tid];
        s_ce[tid] = s;
    }
    if (tid >= 64 && tid < 98) {
        int j = tid - 64;
        float s = 0.f;
        for (int mv = 0; mv < MIR; ++mv) s += acc[OFF_PULLM + mv * 34 + j];
        s_pl[j] = s;
    }
    if (tid < 2) { sh_push[tid] = 0.f; sh_norm[tid] = 0.f; sh_pull[tid] = 0.f; sh_npres[tid] = 0.f; }
    __syncthreads();

    if (tid < 32) {
        int b = tid >> 4, k = (tid & 15) + 1;
        float cnt = acc[OFF_CNT + b * 17 + k];
        if (cnt > 0.f) {
            atomicAdd(&sh_npres[b], 1.f);
            atomicAdd(&sh_pull[b], s_pl[b * 17 + k] / fmaxf(cnt, 1.f));
            const float* c = &acc[OFF_CTR + (b * 17 + k) * 16];
            float n2 = 0.f;
            for (int i = 0; i < 16; ++i) n2 += c[i] * c[i];
            atomicAdd(&sh_norm[b], sqrtf(n2));
        }
    }
    for (int t = tid; t < 240; t += blockDim.x) {
        int b = t / 120, p = t % 120;
        int i = 1, rem = p;
        while (rem >= (16 - i)) { rem -= (16 - i); ++i; }
        int j = i + 1 + rem;
        bool pi = acc[OFF_CNT + b * 17 + i] > 0.f;
        bool pj = acc[OFF_CNT + b * 17 + j] > 0.f;
        if (pi && pj) {
            const float* ci = &acc[OFF_CTR + (b * 17 + i) * 16];
            const float* cj = &acc[OFF_CTR + (b * 17 + j) * 16];
            float d2 = 0.f;
            for (int c = 0; c < 16; ++c) { float dd = ci[c] - cj[c]; d2 += dd * dd; }
            float r = fmaxf(3.0f - sqrtf(d2), 0.f);
            atomicAdd(&sh_push[b], r * r);
        }
    }
    __syncthreads();
    if (tid == 0) {
        float nll = s_ce[0];
        float vcnt = 0.f;
        for (int i = 0; i < 16; ++i) vcnt += s_ce[33 + i];
        float ce = nll / fmaxf(vcnt, 1.f);
        float dsum = 0.f;
        for (int i = 0; i < 16; ++i) {
            float it = s_ce[17 + i], cp = s_ce[1 + i], cg = s_ce[33 + i];
            dsum += (2.f * it + 1e-5f) / (cp + cg + 1e-5f);
        }
        float dice = 1.f - dsum / 16.f;
        float lp = 0.f, lpu = 0.f, ln = 0.f, val = 0.f;
        for (int b = 0; b < 2; ++b) {
            float npres = sh_npres[b];
            lp += sh_pull[b];
            float npairs = npres * (npres - 1.f) * 0.5f;
            lpu += (npairs > 0.f) ? sh_push[b] / fmaxf(npairs, 1.f) : 0.f;
            ln += (npres > 0.f) ? sh_norm[b] / fmaxf(npres, 1.f) : 0.f;
            val += (npres > 0.f) ? 1.f : 0.f;
        }
        float n = fmaxf(val, 1.f);
        float ins = (1.0f * lp + 1.0f * lpu + 0.001f * ln) / n;
        float sem = ce + dice;
        out[0] = sem + ins;
        out[1] = sem;
        out[2] = ce;
        out[3] = dice;
        out[4] = ins;
    }
}

extern "C" void kernel_launch(void* const* d_in, const int* in_sizes, int n_in,
                              void* d_out, int out_size, void* d_ws, size_t ws_size,
                              hipStream_t stream) {
    const float* sem = (const float*)d_in[0];
    const float* emb = (const float*)d_in[1];
    const int* cls = (const int*)d_in[2];
    const int* lab = (const int*)d_in[3];
    float* out = (float*)d_out;
    float* acc = (float*)d_ws;

    hipLaunchKernelGGL(zero_kernel, dim3(23), dim3(1024), 0, stream, acc);
    hipLaunchKernelGGL(phaseA_kernel, dim3(3072), dim3(256), 0, stream, sem, emb, cls, lab, acc);
    hipLaunchKernelGGL(centers_kernel, dim3(1), dim3(1024), 0, stream, acc);
    hipLaunchKernelGGL(phaseB_kernel, dim3(3072), dim3(256), 0, stream, sem, emb, cls, lab, acc);
    hipLaunchKernelGGL(finalize_kernel, dim3(1), dim3(256), 0, stream, acc, out);
}